// Round 6
// baseline (934.259 us; speedup 1.0000x reference)
//
#include <hip/hip_runtime.h>
#include <hip/hip_bf16.h>
#include <math.h>

typedef __attribute__((ext_vector_type(8))) __bf16 bf16x8;
typedef __attribute__((ext_vector_type(4))) __bf16 bf16x4;
typedef __attribute__((ext_vector_type(4))) float f32x4;

// ---------------------------------------------------------------------------
// Wave-local pipeline: each wave owns 16 points end-to-end. NO __syncthreads
// in the main loop — all LDS tiles are wave-private; ordering is the wave's
// own lgkmcnt (compiler-inserted). All tiles use the T2 XOR swizzle
// (byte ^= (row&7)<<4 on the column offset) to break the 8-way bank
// conflicts of 272/144-B row strides.
//  A: 16 x 144 B  (32 bf16 feats, swizzled 16-B slots)
//  H: 16 x 272 B  (128 bf16)
//  F: 16 x 144 B  (64 bf16: 0-15 dfeat, 16-18 d, 19-30 sin, 31-42 cos, 43-63 0)
#define WAVE_A 0
#define WAVE_H 2304
#define WAVE_F 6656
#define WAVE_LDS 8960
#define LDS_TOTAL (4 * WAVE_LDS)       // 35840 B

// ---- sort configuration ---------------------------------------------------
#define NBUCKET 512            // 8x8x8 regions of 16^3 cells (~630 KB grid/region)
#define HB      256            // histogram blocks
// workspace layout (bytes)
#define WS_WP   0UL                    // packed weights     32 KB
#define WS_MAT  32768UL                // [HB][NBUCKET] u32  512 KB
#define WS_TOT  557056UL               // 512 u32
#define WS_BB   559104UL               // 512 u32
#define WS_PERM 561152UL               // perm[N]             8 MB
#define WS_SC   8949760UL              // sorted coords      24 MB
#define WS_SR   34115584UL             // sorted ray_d       24 MB
#define WS_NEED 59281408UL

// ---------------------------------------------------------------------------
// Pack MLP weights into MFMA B-fragment layout.
//   frags 0-7: wd1 | 8-11: wd2 | 12-27: wc1 (rows 43-63 ZERO) | 28-31: wc2
// Frag f: 1024 B, lane l holds B[k=(l>>4)*8+j][n=l&15] of a 32x16 sub-tile.
// ---------------------------------------------------------------------------
__global__ void pack_weights(const float* __restrict__ wd1,
                             const float* __restrict__ wd2,
                             const float* __restrict__ wc1,
                             const float* __restrict__ wc2,
                             __bf16* __restrict__ wp)
{
    int t0 = threadIdx.x;
    for (int it = 0; it < 8; ++it) {
        int t = it * 256 + t0;
        int frag = t >> 6;
        int lane = t & 63;
        int kg = lane >> 4;
        int c  = lane & 15;
        for (int j = 0; j < 8; ++j) {
            int k = kg * 8 + j;
            float v;
            if (frag < 8) {
                v = wd1[k * 128 + frag * 16 + c];
            } else if (frag < 12) {
                v = wd2[((frag - 8) * 32 + k) * 16 + c];
            } else if (frag < 28) {
                int f = frag - 12;
                int kk = (f & 1) * 32 + k;
                v = (kk < 43) ? wc1[kk * 128 + (f >> 1) * 16 + c] : 0.0f;
            } else {
                int kk = (frag - 28) * 32 + k;
                v = (c < 3) ? wc2[kk * 3 + c] : 0.0f;
            }
            wp[frag * 512 + lane * 8 + j] = (__bf16)v;
        }
    }
}

__device__ __forceinline__ int bucket_key(float x, float y, float z) {
    int ix = (int)(x * 127.0f); ix = ix < 0 ? 0 : (ix > 127 ? 127 : ix);
    int iy = (int)(y * 127.0f); iy = iy < 0 ? 0 : (iy > 127 ? 127 : iy);
    int iz = (int)(z * 127.0f); iz = iz < 0 ? 0 : (iz > 127 ? 127 : iz);
    return ((ix >> 4) << 6) | ((iy >> 4) << 3) | (iz >> 4);
}

__global__ __launch_bounds__(256) void hist_lds(const float* __restrict__ coords,
                                                unsigned int* __restrict__ mat,
                                                int ppb)
{
    __shared__ unsigned int lh[NBUCKET];
    for (int i = threadIdx.x; i < NBUCKET; i += 256) lh[i] = 0u;
    __syncthreads();
    int base = blockIdx.x * ppb;
    for (int k = threadIdx.x; k < ppb; k += 256) {
        size_t b = 3 * (size_t)(base + k);
        atomicAdd(&lh[bucket_key(coords[b], coords[b + 1], coords[b + 2])], 1u);
    }
    __syncthreads();
    unsigned int* row = mat + (size_t)blockIdx.x * NBUCKET;
    for (int i = threadIdx.x; i < NBUCKET; i += 256) row[i] = lh[i];
}

// per-bucket exclusive scan over HB blocks (in place) + column totals.
__global__ __launch_bounds__(256) void col_scan(unsigned int* __restrict__ mat,
                                                unsigned int* __restrict__ total)
{
    int wid  = threadIdx.x >> 6;
    int lane = threadIdx.x & 63;
    int bkt  = blockIdx.x * 4 + wid;

    unsigned int v[4];
#pragma unroll
    for (int j = 0; j < 4; ++j)
        v[j] = mat[(size_t)(lane * 4 + j) * NBUCKET + bkt];
    unsigned int pre[4];
    unsigned int sum = 0;
#pragma unroll
    for (int j = 0; j < 4; ++j) { pre[j] = sum; sum += v[j]; }
    unsigned int inc = sum;
    for (int d = 1; d < 64; d <<= 1) {
        unsigned int u = __shfl_up(inc, d);
        if (lane >= d) inc += u;
    }
    unsigned int excl = inc - sum;
#pragma unroll
    for (int j = 0; j < 4; ++j)
        mat[(size_t)(lane * 4 + j) * NBUCKET + bkt] = excl + pre[j];
    if (lane == 63) total[bkt] = inc;
}

// exclusive scan of the 512 bucket totals (single block, 2 per thread).
__global__ __launch_bounds__(256) void bucket_scan(const unsigned int* __restrict__ total,
                                                   unsigned int* __restrict__ bbase)
{
    int t = threadIdx.x;
    unsigned int v0 = total[2 * t], v1 = total[2 * t + 1];
    unsigned int run = v0 + v1;
    unsigned int lane = t & 63;
    int wid = t >> 6;
    unsigned int inc = run;
    for (int d = 1; d < 64; d <<= 1) {
        unsigned int u = __shfl_up(inc, d);
        if (lane >= (unsigned)d) inc += u;
    }
    __shared__ unsigned int wt[4];
    if (lane == 63) wt[wid] = inc;
    __syncthreads();
    unsigned int wbase = 0;
    for (int w = 0; w < wid; ++w) wbase += wt[w];
    unsigned int excl = wbase + inc - run;
    bbase[2 * t]     = excl;
    bbase[2 * t + 1] = excl + v0;
}

__global__ __launch_bounds__(256) void scatter_lds(const float* __restrict__ coords,
                                                   const float* __restrict__ rayd,
                                                   const unsigned int* __restrict__ mat,
                                                   const unsigned int* __restrict__ bbase,
                                                   float* __restrict__ sc,
                                                   float* __restrict__ sr,
                                                   int* __restrict__ perm,
                                                   int ppb)
{
    __shared__ unsigned int cur[NBUCKET];
    const unsigned int* row = mat + (size_t)blockIdx.x * NBUCKET;
    for (int i = threadIdx.x; i < NBUCKET; i += 256)
        cur[i] = bbase[i] + row[i];
    __syncthreads();
    int base = blockIdx.x * ppb;
    for (int k = threadIdx.x; k < ppb; k += 256) {
        int i = base + k;
        size_t b = 3 * (size_t)i;
        float x = coords[b], y = coords[b + 1], z = coords[b + 2];
        unsigned int dst = atomicAdd(&cur[bucket_key(x, y, z)], 1u);
        size_t d3 = 3 * (size_t)dst;
        sc[d3] = x; sc[d3 + 1] = y; sc[d3 + 2] = z;
        sr[d3] = rayd[b]; sr[d3 + 1] = rayd[b + 1]; sr[d3 + 2] = rayd[b + 2];
        perm[dst] = i;
    }
}

// ---------------------------------------------------------------------------
// Fused NeRF forward, wave-local (no barriers in the loop).
// ---------------------------------------------------------------------------
template <bool SORTED>
__global__ __launch_bounds__(256, 2) void nerf_wave(
    const float* __restrict__ coords,
    const float* __restrict__ ray_d,
    const float* __restrict__ grid,     // [128][128][128][32] f32
    const float* __restrict__ bd1,
    const float* __restrict__ bd2,
    const float* __restrict__ bc1,
    const float* __restrict__ bc2,
    const __bf16* __restrict__ wp,
    const int* __restrict__ perm,
    float* __restrict__ out,            // [N][4]
    int ntiles)
{
    __shared__ __align__(16) char lds[LDS_TOTAL];
    const int lane = threadIdx.x & 63;
    const int wid  = threadIdx.x >> 6;
    const int c    = lane & 15;
    const int kg   = lane >> 4;
    char* wlds = lds + wid * WAVE_LDS;

    // ---- all weight fragments + biases into registers ---------------------
    const bf16x8* wpv = (const bf16x8*)wp;
    bf16x8 B1[8], B2[4], B3[16], B4[4];
#pragma unroll
    for (int n = 0; n < 8; ++n)  B1[n] = wpv[n * 64 + lane];
#pragma unroll
    for (int kt = 0; kt < 4; ++kt) B2[kt] = wpv[(8 + kt) * 64 + lane];
#pragma unroll
    for (int f = 0; f < 16; ++f) B3[f] = wpv[(12 + f) * 64 + lane];
#pragma unroll
    for (int kt = 0; kt < 4; ++kt) B4[kt] = wpv[(28 + kt) * 64 + lane];

    float bias1[8], bias3[8];
#pragma unroll
    for (int n = 0; n < 8; ++n) { bias1[n] = bd1[n * 16 + c]; bias3[n] = bc1[n * 16 + c]; }
    const float bias2 = bd2[c];
    const float bias4 = (c < 3) ? bc2[c] : 0.0f;

    // ---- zero F pad cols 43..63 once (wave-private rows) -------------------
    for (int i = lane; i < 16 * 21; i += 64) {
        int row = i / 21, col = 43 + i % 21;
        *(__bf16*)(wlds + WAVE_F + row * 144 + ((col * 2) ^ ((row & 7) << 4))) = (__bf16)0.0f;
    }

    // chunked XCD swizzle over tiles
    const int per = (ntiles + gridDim.x - 1) / gridDim.x;
    int sb = blockIdx.x;
    if ((gridDim.x & 7) == 0)
        sb = (blockIdx.x & 7) * (gridDim.x >> 3) + (blockIdx.x >> 3);

    for (int j = 0; j < per; ++j) {
        const int tile = sb * per + j;
        if (tile >= ntiles) break;
        const int pw = tile * 64 + wid * 16;     // this wave's first point

        // ===== phase 0: loads, trilinear gather -> A, embed -> F ===========
        float rv = (lane < 48) ? ray_d[(size_t)pw * 3 + lane] : 0.0f;
        int pv = 0;
        if constexpr (SORTED) pv = perm[pw + c];
        {
            float cval = (lane < 48) ? coords[(size_t)pw * 3 + lane] : 0.0f;
            const int sub = lane & 7;
#pragma unroll
            for (int r = 0; r < 2; ++r) {
                int q = r * 8 + (lane >> 3);         // wave-local point 0..15
                float cx = __shfl(cval, 3 * q + 0) * 127.0f;
                float cy = __shfl(cval, 3 * q + 1) * 127.0f;
                float cz = __shfl(cval, 3 * q + 2) * 127.0f;
                int ix = (int)floorf(cx); ix = ix < 0 ? 0 : (ix > 126 ? 126 : ix);
                int iy = (int)floorf(cy); iy = iy < 0 ? 0 : (iy > 126 ? 126 : iy);
                int iz = (int)floorf(cz); iz = iz < 0 ? 0 : (iz > 126 ? 126 : iz);
                float tx = cx - (float)ix;
                float ty = cy - (float)iy;
                float tz = cz - (float)iz;

                f32x4 facc = {0.0f, 0.0f, 0.0f, 0.0f};
#pragma unroll
                for (int cc = 0; cc < 8; ++cc) {
                    int ddx = (cc >> 2) & 1, ddy = (cc >> 1) & 1, ddz = cc & 1;
                    float w = (ddx ? tx : 1.0f - tx) *
                              (ddy ? ty : 1.0f - ty) *
                              (ddz ? tz : 1.0f - tz);
                    int idx = ((ix + ddx) << 14) + ((iy + ddy) << 7) + (iz + ddz);
                    f32x4 v = *((const f32x4*)(grid + (size_t)idx * 32) + sub);
                    facc[0] = fmaf(w, v[0], facc[0]);
                    facc[1] = fmaf(w, v[1], facc[1]);
                    facc[2] = fmaf(w, v[2], facc[2]);
                    facc[3] = fmaf(w, v[3], facc[3]);
                }
                bf16x4 hi;
#pragma unroll
                for (int e = 0; e < 4; ++e) hi[e] = (__bf16)facc[e];
                *(bf16x4*)(wlds + WAVE_A + q * 144 +
                           ((sub * 8) ^ ((q & 7) << 4))) = hi;
            }
            // view embedding -> F rows c (wave-private)
            float ddx = __shfl(rv, 3 * c + 0);
            float ddy = __shfl(rv, 3 * c + 1);
            float ddz = __shfl(rv, 3 * c + 2);
            char* Frow = wlds + WAVE_F + c * 144;
            const int xs = (c & 7) << 4;
            if (kg == 0) {
                *(__bf16*)(Frow + ((16 * 2) ^ xs)) = (__bf16)ddx;
                *(__bf16*)(Frow + ((17 * 2) ^ xs)) = (__bf16)ddy;
                *(__bf16*)(Frow + ((18 * 2) ^ xs)) = (__bf16)ddz;
            }
            float fr = (float)(1 << kg);
            float ax = ddx * fr, ay = ddy * fr, az = ddz * fr;
            *(__bf16*)(Frow + (((19 + 3 * kg) * 2 + 0) ^ xs)) = (__bf16)__sinf(ax);
            *(__bf16*)(Frow + (((19 + 3 * kg) * 2 + 2) ^ xs)) = (__bf16)__sinf(ay);
            *(__bf16*)(Frow + (((19 + 3 * kg) * 2 + 4) ^ xs)) = (__bf16)__sinf(az);
            *(__bf16*)(Frow + (((31 + 3 * kg) * 2 + 0) ^ xs)) = (__bf16)__cosf(ax);
            *(__bf16*)(Frow + (((31 + 3 * kg) * 2 + 2) ^ xs)) = (__bf16)__cosf(ay);
            *(__bf16*)(Frow + (((31 + 3 * kg) * 2 + 4) ^ xs)) = (__bf16)__cosf(az);
        }

        // ================= L1: 32 -> 128, relu -> H ========================
        {
            bf16x8 A = *(const bf16x8*)(wlds + WAVE_A + c * 144 +
                                        ((kg * 16) ^ ((c & 7) << 4)));
            f32x4 acc[8];
#pragma unroll
            for (int n = 0; n < 8; ++n) {
                acc[n] = (f32x4){bias1[n], bias1[n], bias1[n], bias1[n]};
                acc[n] = __builtin_amdgcn_mfma_f32_16x16x32_bf16(A, B1[n], acc[n], 0, 0, 0);
            }
#pragma unroll
            for (int n = 0; n < 8; ++n) {
#pragma unroll
                for (int i = 0; i < 4; ++i) {
                    int row = kg * 4 + i;
                    int colb = (n * 16 + c) * 2;
                    *(__bf16*)(wlds + WAVE_H + row * 272 +
                               (colb ^ ((row & 7) << 4))) = (__bf16)fmaxf(acc[n][i], 0.0f);
                }
            }
        }

        // ================= L2: 128 -> 16, density, dfeat -> F ==============
        {
            f32x4 d2 = {bias2, bias2, bias2, bias2};
#pragma unroll
            for (int kt = 0; kt < 4; ++kt) {
                bf16x8 A = *(const bf16x8*)(wlds + WAVE_H + c * 272 +
                                            ((kt * 64 + kg * 16) ^ ((c & 7) << 4)));
                d2 = __builtin_amdgcn_mfma_f32_16x16x32_bf16(A, B2[kt], d2, 0, 0, 0);
            }
#pragma unroll
            for (int i = 0; i < 4; ++i) {
                int row = kg * 4 + i;
                *(__bf16*)(wlds + WAVE_F + row * 144 +
                           ((c * 2) ^ ((row & 7) << 4))) = (__bf16)d2[i];
                int tgt;
                if constexpr (SORTED) tgt = __shfl(pv, row);
                else                  tgt = pw + row;
                if (c == 0)
                    out[(size_t)tgt * 4 + 3] = fmaxf(d2[i], 0.0f);
            }
        }

        // ================= L3: 64 -> 128, relu -> H ========================
        {
            const int xs = (c & 7) << 4;
            bf16x8 A0 = *(const bf16x8*)(wlds + WAVE_F + c * 144 + ((kg * 16) ^ xs));
            bf16x8 A1 = *(const bf16x8*)(wlds + WAVE_F + c * 144 + ((64 + kg * 16) ^ xs));
            f32x4 acc[8];
#pragma unroll
            for (int n = 0; n < 8; ++n) {
                acc[n] = (f32x4){bias3[n], bias3[n], bias3[n], bias3[n]};
                acc[n] = __builtin_amdgcn_mfma_f32_16x16x32_bf16(A0, B3[n * 2],     acc[n], 0, 0, 0);
                acc[n] = __builtin_amdgcn_mfma_f32_16x16x32_bf16(A1, B3[n * 2 + 1], acc[n], 0, 0, 0);
            }
#pragma unroll
            for (int n = 0; n < 8; ++n) {
#pragma unroll
                for (int i = 0; i < 4; ++i) {
                    int row = kg * 4 + i;
                    int colb = (n * 16 + c) * 2;
                    *(__bf16*)(wlds + WAVE_H + row * 272 +
                               (colb ^ ((row & 7) << 4))) = (__bf16)fmaxf(acc[n][i], 0.0f);
                }
            }
        }

        // ================= L4: 128 -> 3, sigmoid, store ====================
        {
            f32x4 o4 = {bias4, bias4, bias4, bias4};
#pragma unroll
            for (int kt = 0; kt < 4; ++kt) {
                bf16x8 A = *(const bf16x8*)(wlds + WAVE_H + c * 272 +
                                            ((kt * 64 + kg * 16) ^ ((c & 7) << 4)));
                o4 = __builtin_amdgcn_mfma_f32_16x16x32_bf16(A, B4[kt], o4, 0, 0, 0);
            }
#pragma unroll
            for (int i = 0; i < 4; ++i) {
                int row = kg * 4 + i;
                int tgt;
                if constexpr (SORTED) tgt = __shfl(pv, row);
                else                  tgt = pw + row;
                float s = 1.0f / (1.0f + __expf(-o4[i]));
                if (c < 3)
                    out[(size_t)tgt * 4 + c] = s;
            }
        }
    }
}

extern "C" void kernel_launch(void* const* d_in, const int* in_sizes, int n_in,
                              void* d_out, int out_size, void* d_ws, size_t ws_size,
                              hipStream_t stream) {
    const float* coords = (const float*)d_in[0];
    const float* ray_d  = (const float*)d_in[1];
    const float* grid   = (const float*)d_in[2];
    const float* wd1    = (const float*)d_in[3];
    const float* bd1    = (const float*)d_in[4];
    const float* wd2    = (const float*)d_in[5];
    const float* bd2    = (const float*)d_in[6];
    const float* wc1    = (const float*)d_in[7];
    const float* bc1    = (const float*)d_in[8];
    const float* wc2    = (const float*)d_in[9];
    const float* bc2    = (const float*)d_in[10];
    float* out = (float*)d_out;

    int N = in_sizes[0] / 3;
    int ntiles = N >> 6;

    char* ws = (char*)d_ws;
    __bf16* wp = (__bf16*)(ws + WS_WP);

    pack_weights<<<1, 256, 0, stream>>>(wd1, wd2, wc1, wc2, wp);

    int blocks = ntiles < 8192 ? ntiles : 8192;

    if (ws_size >= WS_NEED && (N % (HB * 64)) == 0) {
        unsigned int* mat   = (unsigned int*)(ws + WS_MAT);
        unsigned int* total = (unsigned int*)(ws + WS_TOT);
        unsigned int* bbase = (unsigned int*)(ws + WS_BB);
        int*   perm = (int*)(ws + WS_PERM);
        float* sc   = (float*)(ws + WS_SC);
        float* sr   = (float*)(ws + WS_SR);
        int ppb = N / HB;

        hist_lds<<<HB, 256, 0, stream>>>(coords, mat, ppb);
        col_scan<<<NBUCKET / 4, 256, 0, stream>>>(mat, total);
        bucket_scan<<<1, 256, 0, stream>>>(total, bbase);
        scatter_lds<<<HB, 256, 0, stream>>>(coords, ray_d, mat, bbase,
                                            sc, sr, perm, ppb);
        nerf_wave<true><<<blocks, 256, 0, stream>>>(sc, sr, grid,
                                                    bd1, bd2, bc1, bc2,
                                                    wp, perm, out, ntiles);
    } else {
        nerf_wave<false><<<blocks, 256, 0, stream>>>(coords, ray_d, grid,
                                                     bd1, bd2, bc1, bc2,
                                                     wp, nullptr, out, ntiles);
    }
}

// Round 8
// 522.290 us; speedup vs baseline: 1.7888x; 1.7888x over previous
//
#include <hip/hip_runtime.h>
#include <hip/hip_bf16.h>
#include <math.h>

typedef __attribute__((ext_vector_type(8))) __bf16 bf16x8;
typedef __attribute__((ext_vector_type(4))) float f32x4;
typedef __attribute__((ext_vector_type(4))) int i32x4;

// ---- sort configuration ---------------------------------------------------
#define NBUCKET 512            // 8x8x8 regions of 16^3 cells
#define HB      256            // histogram blocks
// workspace layout (bytes)
#define WS_WP   0UL                    // packed weights     32 KB
#define WS_MAT  32768UL                // [HB][NBUCKET] u32  512 KB
#define WS_TOT  557056UL               // 512 u32
#define WS_BB   559104UL               // 512 u32
#define WS_PERM 561152UL               // perm[N]             8 MB
#define WS_SC   8949760UL              // sorted coords      24 MB
#define WS_SR   34115584UL             // sorted ray_d       24 MB
#define WS_NEED 59281408UL

// ---------------------------------------------------------------------------
// Pack MLP weights into MFMA A-fragment layout (weights-as-A).
// Frag f: 1024 B; lane l supplies A[m = l&15][kpos = (l>>4)*8 + j].
//   frags 0-7  : wd1, K-order identity          (out-frag n)
//   frags 8-11 : wd2, K-order PERMUTED          (K-tile kt)
//   frags 12-27: wc1, K-order = F-layout        (out-frag f3, kt3 = frag&1)
//   frags 28-31: wc2, K-order PERMUTED          (K-tile kt)
// PERMUTED K-row for (kt,kg,j): row = 32kt + 16(j>>2) + 4kg + (j&3).
// This makes the D-layout of the previous layer (h[16n+4kg+i] in acc[n][i])
// directly usable as the B-fragment: B(kt) = {acc[2kt][0..3], acc[2kt+1][0..3]}
// with ZERO cross-lane data movement.
// F-layout rows (L3): kt3=0,j<4 -> dfeat dim 4kg+j ; kt3=0,j>=4 -> view dim
// 16+4kg+(j-4) ; kt3=1 -> view dim 32+8kg+j (rows >42 are zero).
// ---------------------------------------------------------------------------
__global__ void pack_weights(const float* __restrict__ wd1,
                             const float* __restrict__ wd2,
                             const float* __restrict__ wc1,
                             const float* __restrict__ wc2,
                             __bf16* __restrict__ wp)
{
    int t0 = threadIdx.x;
    for (int it = 0; it < 8; ++it) {
        int t = it * 256 + t0;
        int frag = t >> 6;
        int lane = t & 63;
        int kg = lane >> 4;
        int c  = lane & 15;
        for (int j = 0; j < 8; ++j) {
            float v;
            if (frag < 8) {
                int k = kg * 8 + j;
                v = wd1[k * 128 + frag * 16 + c];
            } else if (frag < 12) {
                int kt = frag - 8;
                int row = 32 * kt + 16 * (j >> 2) + 4 * kg + (j & 3);
                v = wd2[row * 16 + c];
            } else if (frag < 28) {
                int f = frag - 12;
                int f3 = f >> 1, kt3 = f & 1;
                int row;
                if (kt3 == 0) row = (j < 4) ? (4 * kg + j) : (16 + 4 * kg + (j - 4));
                else          row = 32 + 8 * kg + j;
                v = (row < 43) ? wc1[row * 128 + f3 * 16 + c] : 0.0f;
            } else {
                int kt = frag - 28;
                int row = 32 * kt + 16 * (j >> 2) + 4 * kg + (j & 3);
                v = (c < 3) ? wc2[row * 3 + c] : 0.0f;
            }
            wp[frag * 512 + lane * 8 + j] = (__bf16)v;
        }
    }
}

__device__ __forceinline__ int bucket_key(float x, float y, float z) {
    int ix = (int)(x * 127.0f); ix = ix < 0 ? 0 : (ix > 127 ? 127 : ix);
    int iy = (int)(y * 127.0f); iy = iy < 0 ? 0 : (iy > 127 ? 127 : iy);
    int iz = (int)(z * 127.0f); iz = iz < 0 ? 0 : (iz > 127 ? 127 : iz);
    return ((ix >> 4) << 6) | ((iy >> 4) << 3) | (iz >> 4);
}

__global__ __launch_bounds__(256) void hist_lds(const float* __restrict__ coords,
                                                unsigned int* __restrict__ mat,
                                                int ppb)
{
    __shared__ unsigned int lh[NBUCKET];
    for (int i = threadIdx.x; i < NBUCKET; i += 256) lh[i] = 0u;
    __syncthreads();
    int base = blockIdx.x * ppb;
    for (int k = threadIdx.x; k < ppb; k += 256) {
        size_t b = 3 * (size_t)(base + k);
        atomicAdd(&lh[bucket_key(coords[b], coords[b + 1], coords[b + 2])], 1u);
    }
    __syncthreads();
    unsigned int* row = mat + (size_t)blockIdx.x * NBUCKET;
    for (int i = threadIdx.x; i < NBUCKET; i += 256) row[i] = lh[i];
}

__global__ __launch_bounds__(256) void col_scan(unsigned int* __restrict__ mat,
                                                unsigned int* __restrict__ total)
{
    int wid  = threadIdx.x >> 6;
    int lane = threadIdx.x & 63;
    int bkt  = blockIdx.x * 4 + wid;

    unsigned int v[4];
#pragma unroll
    for (int j = 0; j < 4; ++j)
        v[j] = mat[(size_t)(lane * 4 + j) * NBUCKET + bkt];
    unsigned int pre[4];
    unsigned int sum = 0;
#pragma unroll
    for (int j = 0; j < 4; ++j) { pre[j] = sum; sum += v[j]; }
    unsigned int inc = sum;
    for (int d = 1; d < 64; d <<= 1) {
        unsigned int u = __shfl_up(inc, d);
        if (lane >= d) inc += u;
    }
    unsigned int excl = inc - sum;
#pragma unroll
    for (int j = 0; j < 4; ++j)
        mat[(size_t)(lane * 4 + j) * NBUCKET + bkt] = excl + pre[j];
    if (lane == 63) total[bkt] = inc;
}

__global__ __launch_bounds__(256) void bucket_scan(const unsigned int* __restrict__ total,
                                                   unsigned int* __restrict__ bbase)
{
    int t = threadIdx.x;
    unsigned int v0 = total[2 * t], v1 = total[2 * t + 1];
    unsigned int run = v0 + v1;
    unsigned int lane = t & 63;
    int wid = t >> 6;
    unsigned int inc = run;
    for (int d = 1; d < 64; d <<= 1) {
        unsigned int u = __shfl_up(inc, d);
        if (lane >= (unsigned)d) inc += u;
    }
    __shared__ unsigned int wt[4];
    if (lane == 63) wt[wid] = inc;
    __syncthreads();
    unsigned int wbase = 0;
    for (int w = 0; w < wid; ++w) wbase += wt[w];
    unsigned int excl = wbase + inc - run;
    bbase[2 * t]     = excl;
    bbase[2 * t + 1] = excl + v0;
}

__global__ __launch_bounds__(256) void scatter_lds(const float* __restrict__ coords,
                                                   const float* __restrict__ rayd,
                                                   const unsigned int* __restrict__ mat,
                                                   const unsigned int* __restrict__ bbase,
                                                   float* __restrict__ sc,
                                                   float* __restrict__ sr,
                                                   int* __restrict__ perm,
                                                   int ppb)
{
    __shared__ unsigned int cur[NBUCKET];
    const unsigned int* row = mat + (size_t)blockIdx.x * NBUCKET;
    for (int i = threadIdx.x; i < NBUCKET; i += 256)
        cur[i] = bbase[i] + row[i];
    __syncthreads();
    int base = blockIdx.x * ppb;
    for (int k = threadIdx.x; k < ppb; k += 256) {
        int i = base + k;
        size_t b = 3 * (size_t)i;
        float x = coords[b], y = coords[b + 1], z = coords[b + 2];
        unsigned int dst = atomicAdd(&cur[bucket_key(x, y, z)], 1u);
        size_t d3 = 3 * (size_t)dst;
        sc[d3] = x; sc[d3 + 1] = y; sc[d3 + 2] = z;
        sr[d3] = rayd[b]; sr[d3 + 1] = rayd[b + 1]; sr[d3 + 2] = rayd[b + 2];
        perm[dst] = i;
    }
}

// ---------------------------------------------------------------------------
// Fused NeRF forward: weights-as-A / activations-as-B, co-designed K-order
// packings so every inter-layer handoff is LOCAL registers. No activation
// LDS, no bpermute, no barriers in the loop.
// ---------------------------------------------------------------------------
__device__ __forceinline__ unsigned int pack2(float a, float b) {
    union { __bf16 h[2]; unsigned int u; } x;
    x.h[0] = (__bf16)a; x.h[1] = (__bf16)b;
    return x.u;
}

union BFU { bf16x8 v; unsigned int u[4]; };

template <bool SORTED>
__global__ __launch_bounds__(256)
__attribute__((amdgpu_waves_per_eu(2)))
void nerf_wave(const float* __restrict__ coords,
               const float* __restrict__ ray_d,
               const float* __restrict__ grid,     // [128][128][128][32] f32
               const float* __restrict__ bd1,
               const float* __restrict__ bd2,
               const float* __restrict__ bc1,
               const float* __restrict__ bc2,
               const __bf16* __restrict__ wp,
               const int* __restrict__ perm,
               float* __restrict__ out,            // [N][4]
               int ntiles)
{
    // LDS: [0,16K) L3 weight frags (block-shared); then bias tables (f32).
    __shared__ __align__(16) char lds[16384 + 1152];
    float* ldsB1 = (float*)(lds + 16384);   // bd1[128]
    float* ldsB2 = ldsB1 + 128;             // bd2[16]
    float* ldsB3 = ldsB2 + 16;              // bc1[128]
    float* ldsB4 = ldsB3 + 128;             // bc2 padded[16]

    const int tid = threadIdx.x;
    {
        const i32x4* src = (const i32x4*)(wp + 12 * 512);   // L3 frags
        i32x4* dst = (i32x4*)lds;
        for (int i = tid; i < 1024; i += 256) dst[i] = src[i];
        if (tid < 128) ldsB1[tid] = bd1[tid];
        if (tid < 16)  ldsB2[tid] = bd2[tid];
        if (tid < 128) ldsB3[tid] = bc1[tid];
        if (tid < 16)  ldsB4[tid] = (tid < 3) ? bc2[tid] : 0.0f;
    }
    __syncthreads();   // only barrier in the kernel

    const int lane = tid & 63;
    const int wid  = tid >> 6;
    const int c    = lane & 15;
    const int kg   = lane >> 4;

    // L1 / L2 / L4 weight A-frags in registers (64 VGPR)
    const bf16x8* wpv = (const bf16x8*)wp;
    bf16x8 A1[8], A2[4], A4[4];
#pragma unroll
    for (int n = 0; n < 8; ++n) A1[n] = wpv[n * 64 + lane];
#pragma unroll
    for (int kt = 0; kt < 4; ++kt) A2[kt] = wpv[(8 + kt) * 64 + lane];
#pragma unroll
    for (int kt = 0; kt < 4; ++kt) A4[kt] = wpv[(28 + kt) * 64 + lane];

    const int per = (ntiles + gridDim.x - 1) / gridDim.x;
    int sb = blockIdx.x;
    if ((gridDim.x & 7) == 0)
        sb = (blockIdx.x & 7) * (gridDim.x >> 3) + (blockIdx.x >> 3);

    for (int it = 0; it < per; ++it) {
        const int tile = sb * per + it;
        if (tile >= ntiles) break;
        const int pw = tile * 64 + wid * 16;   // this wave's 16 points

        int pv;
        if constexpr (SORTED) pv = perm[pw + c];
        else                  pv = pw + c;
        float rval = (lane < 48) ? ray_d[(size_t)pw * 3 + lane] : 0.0f;
        float cval = (lane < 48) ? coords[(size_t)pw * 3 + lane] : 0.0f;

        // ---- coords of this lane's point c --------------------------------
        float cx = __shfl(cval, 3 * c + 0) * 127.0f;
        float cy = __shfl(cval, 3 * c + 1) * 127.0f;
        float cz = __shfl(cval, 3 * c + 2) * 127.0f;
        int ix = (int)floorf(cx); ix = ix < 0 ? 0 : (ix > 126 ? 126 : ix);
        int iy = (int)floorf(cy); iy = iy < 0 ? 0 : (iy > 126 ? 126 : iy);
        int iz = (int)floorf(cz); iz = iz < 0 ? 0 : (iz > 126 ? 126 : iz);
        float tx = cx - (float)ix;
        float ty = cy - (float)iy;
        float tz = cz - (float)iz;

        // ---- gather: feats[kg*8 .. kg*8+7] of point c (B-frag layout) -----
        f32x4 fa = {0.0f, 0.0f, 0.0f, 0.0f};
        f32x4 fb = {0.0f, 0.0f, 0.0f, 0.0f};
#pragma unroll
        for (int cc = 0; cc < 8; ++cc) {
            int ddx = (cc >> 2) & 1, ddy = (cc >> 1) & 1, ddz = cc & 1;
            float w = (ddx ? tx : 1.0f - tx) *
                      (ddy ? ty : 1.0f - ty) *
                      (ddz ? tz : 1.0f - tz);
            int idx = ((ix + ddx) << 14) + ((iy + ddy) << 7) + (iz + ddz);
            const f32x4* g = (const f32x4*)(grid + (size_t)idx * 32 + kg * 8);
            f32x4 v0 = g[0], v1 = g[1];
#pragma unroll
            for (int e = 0; e < 4; ++e) {
                fa[e] = fmaf(w, v0[e], fa[e]);
                fb[e] = fmaf(w, v1[e], fb[e]);
            }
        }
        BFU b0;
        b0.u[0] = pack2(fa[0], fa[1]); b0.u[1] = pack2(fa[2], fa[3]);
        b0.u[2] = pack2(fb[0], fb[1]); b0.u[3] = pack2(fb[2], fb[3]);

        // ---- view embedding slots for this lane (dims fixed by kg) --------
        float dxv = __shfl(rval, 3 * c + 0);
        float dyv = __shfl(rval, 3 * c + 1);
        float dzv = __shfl(rval, 3 * c + 2);
        float E0, E1, E2, E3, G0, G1, G2, G3, G4, G5, G6, G7;
        if (kg == 0) {            // E: dims 16-19, G: dims 32-39
            E0 = dxv; E1 = dyv; E2 = dzv; E3 = __sinf(dxv);
            G0 = __cosf(dyv);        G1 = __cosf(dzv);
            G2 = __cosf(2.0f * dxv); G3 = __cosf(2.0f * dyv);
            G4 = __cosf(2.0f * dzv); G5 = __cosf(4.0f * dxv);
            G6 = __cosf(4.0f * dyv); G7 = __cosf(4.0f * dzv);
        } else if (kg == 1) {     // E: dims 20-23, G: dims 40-42 + zeros
            E0 = __sinf(dyv);        E1 = __sinf(dzv);
            E2 = __sinf(2.0f * dxv); E3 = __sinf(2.0f * dyv);
            G0 = __cosf(8.0f * dxv); G1 = __cosf(8.0f * dyv);
            G2 = __cosf(8.0f * dzv);
            G3 = 0.0f; G4 = 0.0f; G5 = 0.0f; G6 = 0.0f; G7 = 0.0f;
        } else if (kg == 2) {     // E: dims 24-27, G: zeros
            E0 = __sinf(2.0f * dzv); E1 = __sinf(4.0f * dxv);
            E2 = __sinf(4.0f * dyv); E3 = __sinf(4.0f * dzv);
            G0 = G1 = G2 = G3 = G4 = G5 = G6 = G7 = 0.0f;
        } else {                  // E: dims 28-31, G: zeros
            E0 = __sinf(8.0f * dxv); E1 = __sinf(8.0f * dyv);
            E2 = __sinf(8.0f * dzv); E3 = __cosf(dxv);
            G0 = G1 = G2 = G3 = G4 = G5 = G6 = G7 = 0.0f;
        }

        // ---- L1: h[16n+4kg+i][c] = wd1^T . feats + bd1 --------------------
        f32x4 acc[8];
#pragma unroll
        for (int n = 0; n < 8; ++n) {
            f32x4 bi = *(const f32x4*)(ldsB1 + n * 16 + kg * 4);
            acc[n] = __builtin_amdgcn_mfma_f32_16x16x32_bf16(A1[n], b0.v, bi, 0, 0, 0);
        }
        unsigned int pk[8][2];
#pragma unroll
        for (int n = 0; n < 8; ++n) {
            pk[n][0] = pack2(fmaxf(acc[n][0], 0.0f), fmaxf(acc[n][1], 0.0f));
            pk[n][1] = pack2(fmaxf(acc[n][2], 0.0f), fmaxf(acc[n][3], 0.0f));
        }

        // ---- L2: dfeat[4kg+i][c]; B(kt) = local {acc[2kt], acc[2kt+1]} ----
        f32x4 accd = *(const f32x4*)(ldsB2 + kg * 4);
#pragma unroll
        for (int kt = 0; kt < 4; ++kt) {
            BFU B;
            B.u[0] = pk[2 * kt][0];     B.u[1] = pk[2 * kt][1];
            B.u[2] = pk[2 * kt + 1][0]; B.u[3] = pk[2 * kt + 1][1];
            accd = __builtin_amdgcn_mfma_f32_16x16x32_bf16(A2[kt], B.v, accd, 0, 0, 0);
        }
        float dens = fmaxf(accd[0], 0.0f);   // dfeat[0]: valid on kg==0 lanes

        // ---- L3: B(kt3=0) = {dfeat local, E}, B(kt3=1) = {G} --------------
        BFU Bk0, Bk1;
        Bk0.u[0] = pack2(accd[0], accd[1]);
        Bk0.u[1] = pack2(accd[2], accd[3]);
        Bk0.u[2] = pack2(E0, E1);
        Bk0.u[3] = pack2(E2, E3);
        Bk1.u[0] = pack2(G0, G1);
        Bk1.u[1] = pack2(G2, G3);
        Bk1.u[2] = pack2(G4, G5);
        Bk1.u[3] = pack2(G6, G7);

        f32x4 acc3[8];
#pragma unroll
        for (int n = 0; n < 8; ++n) {
            f32x4 bi = *(const f32x4*)(ldsB3 + n * 16 + kg * 4);
            bf16x8 w0 = *(const bf16x8*)(lds + (n * 2 + 0) * 1024 + lane * 16);
            bf16x8 w1 = *(const bf16x8*)(lds + (n * 2 + 1) * 1024 + lane * 16);
            acc3[n] = __builtin_amdgcn_mfma_f32_16x16x32_bf16(w0, Bk0.v, bi, 0, 0, 0);
            acc3[n] = __builtin_amdgcn_mfma_f32_16x16x32_bf16(w1, Bk1.v, acc3[n], 0, 0, 0);
        }
        unsigned int pk3[8][2];
#pragma unroll
        for (int n = 0; n < 8; ++n) {
            pk3[n][0] = pack2(fmaxf(acc3[n][0], 0.0f), fmaxf(acc3[n][1], 0.0f));
            pk3[n][1] = pack2(fmaxf(acc3[n][2], 0.0f), fmaxf(acc3[n][3], 0.0f));
        }

        // ---- L4: rgb[4kg+i][c]; B(kt) local ------------------------------
        f32x4 acco = *(const f32x4*)(ldsB4 + kg * 4);
#pragma unroll
        for (int kt = 0; kt < 4; ++kt) {
            BFU B;
            B.u[0] = pk3[2 * kt][0];     B.u[1] = pk3[2 * kt][1];
            B.u[2] = pk3[2 * kt + 1][0]; B.u[3] = pk3[2 * kt + 1][1];
            acco = __builtin_amdgcn_mfma_f32_16x16x32_bf16(A4[kt], B.v, acco, 0, 0, 0);
        }

        // ---- store: lane (kg==0, c) owns point c completely ---------------
        if (lane < 16) {
            f32x4 o;
            o[0] = 1.0f / (1.0f + __expf(-acco[0]));
            o[1] = 1.0f / (1.0f + __expf(-acco[1]));
            o[2] = 1.0f / (1.0f + __expf(-acco[2]));
            o[3] = dens;
            ((f32x4*)out)[pv] = o;
        }
    }
}

extern "C" void kernel_launch(void* const* d_in, const int* in_sizes, int n_in,
                              void* d_out, int out_size, void* d_ws, size_t ws_size,
                              hipStream_t stream) {
    const float* coords = (const float*)d_in[0];
    const float* ray_d  = (const float*)d_in[1];
    const float* grid   = (const float*)d_in[2];
    const float* wd1    = (const float*)d_in[3];
    const float* bd1    = (const float*)d_in[4];
    const float* wd2    = (const float*)d_in[5];
    const float* bd2    = (const float*)d_in[6];
    const float* wc1    = (const float*)d_in[7];
    const float* bc1    = (const float*)d_in[8];
    const float* wc2    = (const float*)d_in[9];
    const float* bc2    = (const float*)d_in[10];
    float* out = (float*)d_out;

    int N = in_sizes[0] / 3;
    int ntiles = N >> 6;

    char* ws = (char*)d_ws;
    __bf16* wp = (__bf16*)(ws + WS_WP);

    pack_weights<<<1, 256, 0, stream>>>(wd1, wd2, wc1, wc2, wp);

    int blocks = ntiles < 8192 ? ntiles : 8192;

    if (ws_size >= WS_NEED && (N % (HB * 64)) == 0) {
        unsigned int* mat   = (unsigned int*)(ws + WS_MAT);
        unsigned int* total = (unsigned int*)(ws + WS_TOT);
        unsigned int* bbase = (unsigned int*)(ws + WS_BB);
        int*   perm = (int*)(ws + WS_PERM);
        float* sc   = (float*)(ws + WS_SC);
        float* sr   = (float*)(ws + WS_SR);
        int ppb = N / HB;

        hist_lds<<<HB, 256, 0, stream>>>(coords, mat, ppb);
        col_scan<<<NBUCKET / 4, 256, 0, stream>>>(mat, total);
        bucket_scan<<<1, 256, 0, stream>>>(total, bbase);
        scatter_lds<<<HB, 256, 0, stream>>>(coords, ray_d, mat, bbase,
                                            sc, sr, perm, ppb);
        nerf_wave<true><<<blocks, 256, 0, stream>>>(sc, sr, grid,
                                                    bd1, bd2, bc1, bc2,
                                                    wp, perm, out, ntiles);
    } else {
        nerf_wave<false><<<blocks, 256, 0, stream>>>(coords, ray_d, grid,
                                                     bd1, bd2, bc1, bc2,
                                                     wp, nullptr, out, ntiles);
    }
}

// Round 9
// 458.608 us; speedup vs baseline: 2.0372x; 1.1389x over previous
//
#include <hip/hip_runtime.h>
#include <hip/hip_bf16.h>
#include <math.h>

typedef __attribute__((ext_vector_type(8))) __bf16 bf16x8;
typedef __attribute__((ext_vector_type(4))) float f32x4;
typedef __attribute__((ext_vector_type(4))) int i32x4;

// ---- sort configuration ---------------------------------------------------
#define NBUCKET 512            // 8x8x8 regions of 16^3 cells
#define HB      256            // histogram blocks
// workspace layout (bytes)
#define WS_WP   0UL                    // packed weights     32 KB
#define WS_MAT  32768UL                // [HB][NBUCKET] u32  512 KB
#define WS_TOT  557056UL               // 512 u32
#define WS_BB   559104UL               // 512 u32
#define WS_PERM 561152UL               // perm[N]             8 MB
#define WS_SC   8949760UL              // sorted coords      24 MB
#define WS_SR   34115584UL             // sorted ray_d       24 MB
#define WS_NEED 59281408UL

// ---------------------------------------------------------------------------
// Pack MLP weights into MFMA A-fragment layout (weights-as-A).
// Frag f: 1024 B; lane l supplies A[m = l&15][kpos = (l>>4)*8 + j].
//   frags 0-7  : wd1, K-order identity          (out-frag n)
//   frags 8-11 : wd2, K-order PERMUTED          (K-tile kt)
//   frags 12-27: wc1, K-order = F-layout        (out-frag f3, kt3 = frag&1)
//   frags 28-31: wc2, K-order PERMUTED          (K-tile kt)
// PERMUTED K-row for (kt,kg,j): row = 32kt + 16(j>>2) + 4kg + (j&3).
// This makes the D-layout of the previous layer (h[16n+4kg+i] in acc[n][i])
// directly usable as the B-fragment: B(kt) = {acc[2kt][0..3], acc[2kt+1][0..3]}
// with ZERO cross-lane data movement.
// F-layout rows (L3): kt3=0,j<4 -> dfeat dim 4kg+j ; kt3=0,j>=4 -> view dim
// 16+4kg+(j-4) ; kt3=1 -> view dim 32+8kg+j (rows >42 are zero).
// ---------------------------------------------------------------------------
__global__ void pack_weights(const float* __restrict__ wd1,
                             const float* __restrict__ wd2,
                             const float* __restrict__ wc1,
                             const float* __restrict__ wc2,
                             __bf16* __restrict__ wp)
{
    int t0 = threadIdx.x;
    for (int it = 0; it < 8; ++it) {
        int t = it * 256 + t0;
        int frag = t >> 6;
        int lane = t & 63;
        int kg = lane >> 4;
        int c  = lane & 15;
        for (int j = 0; j < 8; ++j) {
            float v;
            if (frag < 8) {
                int k = kg * 8 + j;
                v = wd1[k * 128 + frag * 16 + c];
            } else if (frag < 12) {
                int kt = frag - 8;
                int row = 32 * kt + 16 * (j >> 2) + 4 * kg + (j & 3);
                v = wd2[row * 16 + c];
            } else if (frag < 28) {
                int f = frag - 12;
                int f3 = f >> 1, kt3 = f & 1;
                int row;
                if (kt3 == 0) row = (j < 4) ? (4 * kg + j) : (16 + 4 * kg + (j - 4));
                else          row = 32 + 8 * kg + j;
                v = (row < 43) ? wc1[row * 128 + f3 * 16 + c] : 0.0f;
            } else {
                int kt = frag - 28;
                int row = 32 * kt + 16 * (j >> 2) + 4 * kg + (j & 3);
                v = (c < 3) ? wc2[row * 3 + c] : 0.0f;
            }
            wp[frag * 512 + lane * 8 + j] = (__bf16)v;
        }
    }
}

__device__ __forceinline__ int bucket_key(float x, float y, float z) {
    int ix = (int)(x * 127.0f); ix = ix < 0 ? 0 : (ix > 127 ? 127 : ix);
    int iy = (int)(y * 127.0f); iy = iy < 0 ? 0 : (iy > 127 ? 127 : iy);
    int iz = (int)(z * 127.0f); iz = iz < 0 ? 0 : (iz > 127 ? 127 : iz);
    return ((ix >> 4) << 6) | ((iy >> 4) << 3) | (iz >> 4);
}

__global__ __launch_bounds__(256) void hist_lds(const float* __restrict__ coords,
                                                unsigned int* __restrict__ mat,
                                                int ppb)
{
    __shared__ unsigned int lh[NBUCKET];
    for (int i = threadIdx.x; i < NBUCKET; i += 256) lh[i] = 0u;
    __syncthreads();
    int base = blockIdx.x * ppb;
    for (int k = threadIdx.x; k < ppb; k += 256) {
        size_t b = 3 * (size_t)(base + k);
        atomicAdd(&lh[bucket_key(coords[b], coords[b + 1], coords[b + 2])], 1u);
    }
    __syncthreads();
    unsigned int* row = mat + (size_t)blockIdx.x * NBUCKET;
    for (int i = threadIdx.x; i < NBUCKET; i += 256) row[i] = lh[i];
}

__global__ __launch_bounds__(256) void col_scan(unsigned int* __restrict__ mat,
                                                unsigned int* __restrict__ total)
{
    int wid  = threadIdx.x >> 6;
    int lane = threadIdx.x & 63;
    int bkt  = blockIdx.x * 4 + wid;

    unsigned int v[4];
#pragma unroll
    for (int j = 0; j < 4; ++j)
        v[j] = mat[(size_t)(lane * 4 + j) * NBUCKET + bkt];
    unsigned int pre[4];
    unsigned int sum = 0;
#pragma unroll
    for (int j = 0; j < 4; ++j) { pre[j] = sum; sum += v[j]; }
    unsigned int inc = sum;
    for (int d = 1; d < 64; d <<= 1) {
        unsigned int u = __shfl_up(inc, d);
        if (lane >= d) inc += u;
    }
    unsigned int excl = inc - sum;
#pragma unroll
    for (int j = 0; j < 4; ++j)
        mat[(size_t)(lane * 4 + j) * NBUCKET + bkt] = excl + pre[j];
    if (lane == 63) total[bkt] = inc;
}

__global__ __launch_bounds__(256) void bucket_scan(const unsigned int* __restrict__ total,
                                                   unsigned int* __restrict__ bbase)
{
    int t = threadIdx.x;
    unsigned int v0 = total[2 * t], v1 = total[2 * t + 1];
    unsigned int run = v0 + v1;
    unsigned int lane = t & 63;
    int wid = t >> 6;
    unsigned int inc = run;
    for (int d = 1; d < 64; d <<= 1) {
        unsigned int u = __shfl_up(inc, d);
        if (lane >= (unsigned)d) inc += u;
    }
    __shared__ unsigned int wt[4];
    if (lane == 63) wt[wid] = inc;
    __syncthreads();
    unsigned int wbase = 0;
    for (int w = 0; w < wid; ++w) wbase += wt[w];
    unsigned int excl = wbase + inc - run;
    bbase[2 * t]     = excl;
    bbase[2 * t + 1] = excl + v0;
}

__global__ __launch_bounds__(256) void scatter_lds(const float* __restrict__ coords,
                                                   const float* __restrict__ rayd,
                                                   const unsigned int* __restrict__ mat,
                                                   const unsigned int* __restrict__ bbase,
                                                   float* __restrict__ sc,
                                                   float* __restrict__ sr,
                                                   int* __restrict__ perm,
                                                   int ppb)
{
    __shared__ unsigned int cur[NBUCKET];
    const unsigned int* row = mat + (size_t)blockIdx.x * NBUCKET;
    for (int i = threadIdx.x; i < NBUCKET; i += 256)
        cur[i] = bbase[i] + row[i];
    __syncthreads();
    int base = blockIdx.x * ppb;
    for (int k = threadIdx.x; k < ppb; k += 256) {
        int i = base + k;
        size_t b = 3 * (size_t)i;
        float x = coords[b], y = coords[b + 1], z = coords[b + 2];
        unsigned int dst = atomicAdd(&cur[bucket_key(x, y, z)], 1u);
        size_t d3 = 3 * (size_t)dst;
        sc[d3] = x; sc[d3 + 1] = y; sc[d3 + 2] = z;
        sr[d3] = rayd[b]; sr[d3 + 1] = rayd[b + 1]; sr[d3 + 2] = rayd[b + 2];
        perm[dst] = i;
    }
}

// ---------------------------------------------------------------------------
// Fused NeRF forward: weights-as-A / activations-as-B with co-designed
// K-order packings (all inter-layer handoffs are LOCAL registers).
// ALL weight fragments live in block LDS (freed 64 VGPR -> 4 waves/SIMD);
// coords/ray/perm for the next tile are prefetched at the top of the body.
// ---------------------------------------------------------------------------
__device__ __forceinline__ unsigned int pack2(float a, float b) {
    union { __bf16 h[2]; unsigned int u; } x;
    x.h[0] = (__bf16)a; x.h[1] = (__bf16)b;
    return x.u;
}

union BFU { bf16x8 v; unsigned int u[4]; };

template <bool SORTED>
__global__ __launch_bounds__(256)
__attribute__((amdgpu_waves_per_eu(4)))
void nerf_wave(const float* __restrict__ coords,
               const float* __restrict__ ray_d,
               const float* __restrict__ grid,     // [128][128][128][32] f32
               const float* __restrict__ bd1,
               const float* __restrict__ bd2,
               const float* __restrict__ bc1,
               const float* __restrict__ bc2,
               const __bf16* __restrict__ wp,
               const int* __restrict__ perm,
               float* __restrict__ out,            // [N][4]
               int ntiles)
{
    // LDS: [0,32K) all 32 weight frags (block-shared); then bias tables.
    __shared__ __align__(16) char lds[32768 + 1152];
    float* ldsB1 = (float*)(lds + 32768);   // bd1[128]
    float* ldsB2 = ldsB1 + 128;             // bd2[16]
    float* ldsB3 = ldsB2 + 16;              // bc1[128]
    float* ldsB4 = ldsB3 + 128;             // bc2 padded[16]

    const int tid = threadIdx.x;
    {
        const i32x4* src = (const i32x4*)wp;
        i32x4* dst = (i32x4*)lds;
        for (int i = tid; i < 2048; i += 256) dst[i] = src[i];
        if (tid < 128) ldsB1[tid] = bd1[tid];
        if (tid < 16)  ldsB2[tid] = bd2[tid];
        if (tid < 128) ldsB3[tid] = bc1[tid];
        if (tid < 16)  ldsB4[tid] = (tid < 3) ? bc2[tid] : 0.0f;
    }
    __syncthreads();   // only barrier in the kernel

    const int lane = tid & 63;
    const int wid  = tid >> 6;
    const int c    = lane & 15;
    const int kg   = lane >> 4;
    const int lb   = lane * 16;            // byte offset of this lane's frag row

    const int per = (ntiles + gridDim.x - 1) / gridDim.x;
    int sb = blockIdx.x;
    if ((gridDim.x & 7) == 0)
        sb = (blockIdx.x & 7) * (gridDim.x >> 3) + (blockIdx.x >> 3);

    // ---- prefetch iteration 0 ------------------------------------------------
    const int pw0 = (sb * per) * 64 + wid * 16;
    float rval = (lane < 48) ? ray_d[(size_t)pw0 * 3 + lane] : 0.0f;
    float cval = (lane < 48) ? coords[(size_t)pw0 * 3 + lane] : 0.0f;
    int pv;
    if constexpr (SORTED) pv = perm[pw0 + c];
    else                  pv = pw0 + c;

    for (int it = 0; it < per; ++it) {
        const int tile = sb * per + it;
        if (tile >= ntiles) break;

        // current iteration's preloaded values
        float rv = rval, cv = cval;
        const int pvc = pv;

        // ---- prefetch next iteration (clamped; overlaps this tile's MLP) --
        {
            int tn = tile + 1 < ntiles ? tile + 1 : tile;
            const int pwn = tn * 64 + wid * 16;
            rval = (lane < 48) ? ray_d[(size_t)pwn * 3 + lane] : 0.0f;
            cval = (lane < 48) ? coords[(size_t)pwn * 3 + lane] : 0.0f;
            if constexpr (SORTED) pv = perm[pwn + c];
            else                  pv = pwn + c;
        }

        // ---- coords of this lane's point c --------------------------------
        float cx = __shfl(cv, 3 * c + 0) * 127.0f;
        float cy = __shfl(cv, 3 * c + 1) * 127.0f;
        float cz = __shfl(cv, 3 * c + 2) * 127.0f;
        int ix = (int)floorf(cx); ix = ix < 0 ? 0 : (ix > 126 ? 126 : ix);
        int iy = (int)floorf(cy); iy = iy < 0 ? 0 : (iy > 126 ? 126 : iy);
        int iz = (int)floorf(cz); iz = iz < 0 ? 0 : (iz > 126 ? 126 : iz);
        float tx = cx - (float)ix;
        float ty = cy - (float)iy;
        float tz = cz - (float)iz;

        // ---- gather: feats[kg*8 .. kg*8+7] of point c (B-frag layout) -----
        f32x4 fa = {0.0f, 0.0f, 0.0f, 0.0f};
        f32x4 fb = {0.0f, 0.0f, 0.0f, 0.0f};
#pragma unroll
        for (int cc = 0; cc < 8; ++cc) {
            int ddx = (cc >> 2) & 1, ddy = (cc >> 1) & 1, ddz = cc & 1;
            float w = (ddx ? tx : 1.0f - tx) *
                      (ddy ? ty : 1.0f - ty) *
                      (ddz ? tz : 1.0f - tz);
            int idx = ((ix + ddx) << 14) + ((iy + ddy) << 7) + (iz + ddz);
            const f32x4* g = (const f32x4*)(grid + (size_t)idx * 32 + kg * 8);
            f32x4 v0 = g[0], v1 = g[1];
#pragma unroll
            for (int e = 0; e < 4; ++e) {
                fa[e] = fmaf(w, v0[e], fa[e]);
                fb[e] = fmaf(w, v1[e], fb[e]);
            }
        }
        BFU b0;
        b0.u[0] = pack2(fa[0], fa[1]); b0.u[1] = pack2(fa[2], fa[3]);
        b0.u[2] = pack2(fb[0], fb[1]); b0.u[3] = pack2(fb[2], fb[3]);

        // ---- view embedding slots for this lane (dims fixed by kg) --------
        float dxv = __shfl(rv, 3 * c + 0);
        float dyv = __shfl(rv, 3 * c + 1);
        float dzv = __shfl(rv, 3 * c + 2);
        float E0, E1, E2, E3, G0, G1, G2, G3, G4, G5, G6, G7;
        if (kg == 0) {            // E: dims 16-19, G: dims 32-39
            E0 = dxv; E1 = dyv; E2 = dzv; E3 = __sinf(dxv);
            G0 = __cosf(dyv);        G1 = __cosf(dzv);
            G2 = __cosf(2.0f * dxv); G3 = __cosf(2.0f * dyv);
            G4 = __cosf(2.0f * dzv); G5 = __cosf(4.0f * dxv);
            G6 = __cosf(4.0f * dyv); G7 = __cosf(4.0f * dzv);
        } else if (kg == 1) {     // E: dims 20-23, G: dims 40-42 + zeros
            E0 = __sinf(dyv);        E1 = __sinf(dzv);
            E2 = __sinf(2.0f * dxv); E3 = __sinf(2.0f * dyv);
            G0 = __cosf(8.0f * dxv); G1 = __cosf(8.0f * dyv);
            G2 = __cosf(8.0f * dzv);
            G3 = 0.0f; G4 = 0.0f; G5 = 0.0f; G6 = 0.0f; G7 = 0.0f;
        } else if (kg == 2) {     // E: dims 24-27, G: zeros
            E0 = __sinf(2.0f * dzv); E1 = __sinf(4.0f * dxv);
            E2 = __sinf(4.0f * dyv); E3 = __sinf(4.0f * dzv);
            G0 = G1 = G2 = G3 = G4 = G5 = G6 = G7 = 0.0f;
        } else {                  // E: dims 28-31, G: zeros
            E0 = __sinf(8.0f * dxv); E1 = __sinf(8.0f * dyv);
            E2 = __sinf(8.0f * dzv); E3 = __cosf(dxv);
            G0 = G1 = G2 = G3 = G4 = G5 = G6 = G7 = 0.0f;
        }

        // ---- L1: h[16n+4kg+i][c] = wd1^T . feats + bd1 --------------------
        f32x4 acc[8];
#pragma unroll
        for (int n = 0; n < 8; ++n) {
            f32x4 bi = *(const f32x4*)(ldsB1 + n * 16 + kg * 4);
            bf16x8 A = *(const bf16x8*)(lds + n * 1024 + lb);
            acc[n] = __builtin_amdgcn_mfma_f32_16x16x32_bf16(A, b0.v, bi, 0, 0, 0);
        }
        unsigned int pk[8][2];
#pragma unroll
        for (int n = 0; n < 8; ++n) {
            pk[n][0] = pack2(fmaxf(acc[n][0], 0.0f), fmaxf(acc[n][1], 0.0f));
            pk[n][1] = pack2(fmaxf(acc[n][2], 0.0f), fmaxf(acc[n][3], 0.0f));
        }

        // ---- L2: dfeat[4kg+i][c]; B(kt) = local {acc[2kt], acc[2kt+1]} ----
        f32x4 accd = *(const f32x4*)(ldsB2 + kg * 4);
#pragma unroll
        for (int kt = 0; kt < 4; ++kt) {
            BFU B;
            B.u[0] = pk[2 * kt][0];     B.u[1] = pk[2 * kt][1];
            B.u[2] = pk[2 * kt + 1][0]; B.u[3] = pk[2 * kt + 1][1];
            bf16x8 A = *(const bf16x8*)(lds + (8 + kt) * 1024 + lb);
            accd = __builtin_amdgcn_mfma_f32_16x16x32_bf16(A, B.v, accd, 0, 0, 0);
        }
        float dens = fmaxf(accd[0], 0.0f);   // dfeat[0]: valid on kg==0 lanes

        // ---- L3: B(kt3=0) = {dfeat local, E}, B(kt3=1) = {G} --------------
        BFU Bk0, Bk1;
        Bk0.u[0] = pack2(accd[0], accd[1]);
        Bk0.u[1] = pack2(accd[2], accd[3]);
        Bk0.u[2] = pack2(E0, E1);
        Bk0.u[3] = pack2(E2, E3);
        Bk1.u[0] = pack2(G0, G1);
        Bk1.u[1] = pack2(G2, G3);
        Bk1.u[2] = pack2(G4, G5);
        Bk1.u[3] = pack2(G6, G7);

        f32x4 acc3[8];
#pragma unroll
        for (int n = 0; n < 8; ++n) {
            f32x4 bi = *(const f32x4*)(ldsB3 + n * 16 + kg * 4);
            bf16x8 w0 = *(const bf16x8*)(lds + (12 + n * 2 + 0) * 1024 + lb);
            bf16x8 w1 = *(const bf16x8*)(lds + (12 + n * 2 + 1) * 1024 + lb);
            acc3[n] = __builtin_amdgcn_mfma_f32_16x16x32_bf16(w0, Bk0.v, bi, 0, 0, 0);
            acc3[n] = __builtin_amdgcn_mfma_f32_16x16x32_bf16(w1, Bk1.v, acc3[n], 0, 0, 0);
        }
        unsigned int pk3[8][2];
#pragma unroll
        for (int n = 0; n < 8; ++n) {
            pk3[n][0] = pack2(fmaxf(acc3[n][0], 0.0f), fmaxf(acc3[n][1], 0.0f));
            pk3[n][1] = pack2(fmaxf(acc3[n][2], 0.0f), fmaxf(acc3[n][3], 0.0f));
        }

        // ---- L4: rgb[4kg+i][c]; B(kt) local ------------------------------
        f32x4 acco = *(const f32x4*)(ldsB4 + kg * 4);
#pragma unroll
        for (int kt = 0; kt < 4; ++kt) {
            BFU B;
            B.u[0] = pk3[2 * kt][0];     B.u[1] = pk3[2 * kt][1];
            B.u[2] = pk3[2 * kt + 1][0]; B.u[3] = pk3[2 * kt + 1][1];
            bf16x8 A = *(const bf16x8*)(lds + (28 + kt) * 1024 + lb);
            acco = __builtin_amdgcn_mfma_f32_16x16x32_bf16(A, B.v, acco, 0, 0, 0);
        }

        // ---- store: lane (kg==0, c) owns point c completely ---------------
        if (lane < 16) {
            f32x4 o;
            o[0] = 1.0f / (1.0f + __expf(-acco[0]));
            o[1] = 1.0f / (1.0f + __expf(-acco[1]));
            o[2] = 1.0f / (1.0f + __expf(-acco[2]));
            o[3] = dens;
            ((f32x4*)out)[pvc] = o;
        }
    }
}

extern "C" void kernel_launch(void* const* d_in, const int* in_sizes, int n_in,
                              void* d_out, int out_size, void* d_ws, size_t ws_size,
                              hipStream_t stream) {
    const float* coords = (const float*)d_in[0];
    const float* ray_d  = (const float*)d_in[1];
    const float* grid   = (const float*)d_in[2];
    const float* wd1    = (const float*)d_in[3];
    const float* bd1    = (const float*)d_in[4];
    const float* wd2    = (const float*)d_in[5];
    const float* bd2    = (const float*)d_in[6];
    const float* wc1    = (const float*)d_in[7];
    const float* bc1    = (const float*)d_in[8];
    const float* wc2    = (const float*)d_in[9];
    const float* bc2    = (const float*)d_in[10];
    float* out = (float*)d_out;

    int N = in_sizes[0] / 3;
    int ntiles = N >> 6;

    char* ws = (char*)d_ws;
    __bf16* wp = (__bf16*)(ws + WS_WP);

    pack_weights<<<1, 256, 0, stream>>>(wd1, wd2, wc1, wc2, wp);

    int blocks = ntiles < 8192 ? ntiles : 8192;

    if (ws_size >= WS_NEED && (N % (HB * 64)) == 0) {
        unsigned int* mat   = (unsigned int*)(ws + WS_MAT);
        unsigned int* total = (unsigned int*)(ws + WS_TOT);
        unsigned int* bbase = (unsigned int*)(ws + WS_BB);
        int*   perm = (int*)(ws + WS_PERM);
        float* sc   = (float*)(ws + WS_SC);
        float* sr   = (float*)(ws + WS_SR);
        int ppb = N / HB;

        hist_lds<<<HB, 256, 0, stream>>>(coords, mat, ppb);
        col_scan<<<NBUCKET / 4, 256, 0, stream>>>(mat, total);
        bucket_scan<<<1, 256, 0, stream>>>(total, bbase);
        scatter_lds<<<HB, 256, 0, stream>>>(coords, ray_d, mat, bbase,
                                            sc, sr, perm, ppb);
        nerf_wave<true><<<blocks, 256, 0, stream>>>(sc, sr, grid,
                                                    bd1, bd2, bc1, bc2,
                                                    wp, perm, out, ntiles);
    } else {
        nerf_wave<false><<<blocks, 256, 0, stream>>>(coords, ray_d, grid,
                                                     bd1, bd2, bc1, bc2,
                                                     wp, nullptr, out, ntiles);
    }
}

// Round 10
// 395.123 us; speedup vs baseline: 2.3645x; 1.1607x over previous
//
#include <hip/hip_runtime.h>
#include <hip/hip_bf16.h>
#include <math.h>

typedef __attribute__((ext_vector_type(8))) __bf16 bf16x8;
typedef __attribute__((ext_vector_type(4))) float f32x4;
typedef __attribute__((ext_vector_type(4))) int i32x4;

// ---- sort configuration ---------------------------------------------------
#define NBUCKET 512            // 8x8x8 regions of 16^3 cells
#define HB      256            // histogram blocks
// workspace layout (bytes) -- perm-only sort (no coord/ray staging)
#define WS_WP   0UL                    // packed weights     32 KB
#define WS_MAT  32768UL                // [HB][NBUCKET] u32  512 KB
#define WS_TOT  557056UL               // 512 u32
#define WS_BB   559104UL               // 512 u32
#define WS_PERM 561152UL               // perm[N]             8 MB
#define WS_NEED 8949760UL

// ---------------------------------------------------------------------------
// Pack MLP weights into MFMA A-fragment layout (weights-as-A).
// Frag f: 1024 B; lane l supplies A[m = l&15][kpos = (l>>4)*8 + j].
//   frags 0-7  : wd1, K-order identity          (out-frag n)
//   frags 8-11 : wd2, K-order PERMUTED          (K-tile kt)
//   frags 12-27: wc1, K-order = F-layout        (out-frag f3, kt3 = frag&1)
//   frags 28-31: wc2, K-order PERMUTED          (K-tile kt)
// PERMUTED K-row for (kt,kg,j): row = 32kt + 16(j>>2) + 4kg + (j&3) --
// makes the previous layer's D-layout directly usable as B-fragments.
// F-layout rows (L3): kt3=0,j<4 -> dfeat 4kg+j ; kt3=0,j>=4 -> view
// 16+4kg+(j-4) ; kt3=1 -> view 32+8kg+j (rows >42 zero).
// ---------------------------------------------------------------------------
__global__ void pack_weights(const float* __restrict__ wd1,
                             const float* __restrict__ wd2,
                             const float* __restrict__ wc1,
                             const float* __restrict__ wc2,
                             __bf16* __restrict__ wp)
{
    int t0 = threadIdx.x;
    for (int it = 0; it < 8; ++it) {
        int t = it * 256 + t0;
        int frag = t >> 6;
        int lane = t & 63;
        int kg = lane >> 4;
        int c  = lane & 15;
        for (int j = 0; j < 8; ++j) {
            float v;
            if (frag < 8) {
                int k = kg * 8 + j;
                v = wd1[k * 128 + frag * 16 + c];
            } else if (frag < 12) {
                int kt = frag - 8;
                int row = 32 * kt + 16 * (j >> 2) + 4 * kg + (j & 3);
                v = wd2[row * 16 + c];
            } else if (frag < 28) {
                int f = frag - 12;
                int f3 = f >> 1, kt3 = f & 1;
                int row;
                if (kt3 == 0) row = (j < 4) ? (4 * kg + j) : (16 + 4 * kg + (j - 4));
                else          row = 32 + 8 * kg + j;
                v = (row < 43) ? wc1[row * 128 + f3 * 16 + c] : 0.0f;
            } else {
                int kt = frag - 28;
                int row = 32 * kt + 16 * (j >> 2) + 4 * kg + (j & 3);
                v = (c < 3) ? wc2[row * 3 + c] : 0.0f;
            }
            wp[frag * 512 + lane * 8 + j] = (__bf16)v;
        }
    }
}

__device__ __forceinline__ int bucket_key(float x, float y, float z) {
    int ix = (int)(x * 127.0f); ix = ix < 0 ? 0 : (ix > 127 ? 127 : ix);
    int iy = (int)(y * 127.0f); iy = iy < 0 ? 0 : (iy > 127 ? 127 : iy);
    int iz = (int)(z * 127.0f); iz = iz < 0 ? 0 : (iz > 127 ? 127 : iz);
    return ((ix >> 4) << 6) | ((iy >> 4) << 3) | (iz >> 4);
}

__global__ __launch_bounds__(256) void hist_lds(const float* __restrict__ coords,
                                                unsigned int* __restrict__ mat,
                                                int ppb)
{
    __shared__ unsigned int lh[NBUCKET];
    for (int i = threadIdx.x; i < NBUCKET; i += 256) lh[i] = 0u;
    __syncthreads();
    int base = blockIdx.x * ppb;
    for (int k = threadIdx.x; k < ppb; k += 256) {
        size_t b = 3 * (size_t)(base + k);
        atomicAdd(&lh[bucket_key(coords[b], coords[b + 1], coords[b + 2])], 1u);
    }
    __syncthreads();
    unsigned int* row = mat + (size_t)blockIdx.x * NBUCKET;
    for (int i = threadIdx.x; i < NBUCKET; i += 256) row[i] = lh[i];
}

__global__ __launch_bounds__(256) void col_scan(unsigned int* __restrict__ mat,
                                                unsigned int* __restrict__ total)
{
    int wid  = threadIdx.x >> 6;
    int lane = threadIdx.x & 63;
    int bkt  = blockIdx.x * 4 + wid;

    unsigned int v[4];
#pragma unroll
    for (int j = 0; j < 4; ++j)
        v[j] = mat[(size_t)(lane * 4 + j) * NBUCKET + bkt];
    unsigned int pre[4];
    unsigned int sum = 0;
#pragma unroll
    for (int j = 0; j < 4; ++j) { pre[j] = sum; sum += v[j]; }
    unsigned int inc = sum;
    for (int d = 1; d < 64; d <<= 1) {
        unsigned int u = __shfl_up(inc, d);
        if (lane >= d) inc += u;
    }
    unsigned int excl = inc - sum;
#pragma unroll
    for (int j = 0; j < 4; ++j)
        mat[(size_t)(lane * 4 + j) * NBUCKET + bkt] = excl + pre[j];
    if (lane == 63) total[bkt] = inc;
}

__global__ __launch_bounds__(256) void bucket_scan(const unsigned int* __restrict__ total,
                                                   unsigned int* __restrict__ bbase)
{
    int t = threadIdx.x;
    unsigned int v0 = total[2 * t], v1 = total[2 * t + 1];
    unsigned int run = v0 + v1;
    unsigned int lane = t & 63;
    int wid = t >> 6;
    unsigned int inc = run;
    for (int d = 1; d < 64; d <<= 1) {
        unsigned int u = __shfl_up(inc, d);
        if (lane >= (unsigned)d) inc += u;
    }
    __shared__ unsigned int wt[4];
    if (lane == 63) wt[wid] = inc;
    __syncthreads();
    unsigned int wbase = 0;
    for (int w = 0; w < wid; ++w) wbase += wt[w];
    unsigned int excl = wbase + inc - run;
    bbase[2 * t]     = excl;
    bbase[2 * t + 1] = excl + v0;
}

// scatter: writes ONLY perm (sorted slot -> original index). 8 MB output.
__global__ __launch_bounds__(256) void scatter_perm(const float* __restrict__ coords,
                                                    const unsigned int* __restrict__ mat,
                                                    const unsigned int* __restrict__ bbase,
                                                    int* __restrict__ perm,
                                                    int ppb)
{
    __shared__ unsigned int cur[NBUCKET];
    const unsigned int* row = mat + (size_t)blockIdx.x * NBUCKET;
    for (int i = threadIdx.x; i < NBUCKET; i += 256)
        cur[i] = bbase[i] + row[i];
    __syncthreads();
    int base = blockIdx.x * ppb;
    for (int k = threadIdx.x; k < ppb; k += 256) {
        int i = base + k;
        size_t b = 3 * (size_t)i;
        unsigned int dst = atomicAdd(&cur[bucket_key(coords[b], coords[b + 1], coords[b + 2])], 1u);
        perm[dst] = i;
    }
}

// ---------------------------------------------------------------------------
// Fused NeRF forward: weights-as-A / activations-as-B with co-designed
// K-order packings (all inter-layer handoffs are LOCAL registers).
// Weights in block LDS; coords/ray loaded via perm indirection with a
// 2-deep (perm) / 1-deep (coords,ray) software pipeline.
// ---------------------------------------------------------------------------
__device__ __forceinline__ unsigned int pack2(float a, float b) {
    union { __bf16 h[2]; unsigned int u; } x;
    x.h[0] = (__bf16)a; x.h[1] = (__bf16)b;
    return x.u;
}

union BFU { bf16x8 v; unsigned int u[4]; };

template <bool SORTED>
__global__ __launch_bounds__(256)
__attribute__((amdgpu_waves_per_eu(4)))
void nerf_wave(const float* __restrict__ coords,   // ORIGINAL order
               const float* __restrict__ ray_d,    // ORIGINAL order
               const float* __restrict__ grid,     // [128][128][128][32] f32
               const float* __restrict__ bd1,
               const float* __restrict__ bd2,
               const float* __restrict__ bc1,
               const float* __restrict__ bc2,
               const __bf16* __restrict__ wp,
               const int* __restrict__ perm,       // sorted slot -> original
               float* __restrict__ out,            // [N][4]
               int ntiles)
{
    // LDS: [0,32K) all 32 weight frags (block-shared); then bias tables.
    __shared__ __align__(16) char lds[32768 + 1152];
    float* ldsB1 = (float*)(lds + 32768);   // bd1[128]
    float* ldsB2 = ldsB1 + 128;             // bd2[16]
    float* ldsB3 = ldsB2 + 16;              // bc1[128]
    float* ldsB4 = ldsB3 + 128;             // bc2 padded[16]

    const int tid = threadIdx.x;
    {
        const i32x4* src = (const i32x4*)wp;
        i32x4* dst = (i32x4*)lds;
        for (int i = tid; i < 2048; i += 256) dst[i] = src[i];
        if (tid < 128) ldsB1[tid] = bd1[tid];
        if (tid < 16)  ldsB2[tid] = bd2[tid];
        if (tid < 128) ldsB3[tid] = bc1[tid];
        if (tid < 16)  ldsB4[tid] = (tid < 3) ? bc2[tid] : 0.0f;
    }
    __syncthreads();   // only barrier in the kernel

    const int lane = tid & 63;
    const int wid  = tid >> 6;
    const int c    = lane & 15;
    const int kg   = lane >> 4;
    const int lb   = lane * 16;            // byte offset of lane's frag row
    const int q3   = lane / 3;             // point index for coord loads
    const int e3   = lane - 3 * q3;        // element (x/y/z)

    const int per = (ntiles + gridDim.x - 1) / gridDim.x;
    int sb = blockIdx.x;
    if ((gridDim.x & 7) == 0)
        sb = (blockIdx.x & 7) * (gridDim.x >> 3) + (blockIdx.x >> 3);

    // ---- pipeline prologue -------------------------------------------------
    int t0 = sb * per;       if (t0 >= ntiles) t0 = ntiles - 1;
    int t1 = sb * per + 1;   if (t1 >= ntiles) t1 = ntiles - 1;
    int pvA, pvB;            // perm of this lane's point c, iters it / it+1
    if constexpr (SORTED) pvA = perm[t0 * 64 + wid * 16 + c];
    else                  pvA = t0 * 64 + wid * 16 + c;
    {
        int pq = __shfl(pvA, q3);
        // loads below guarded by lane<48
        pvB = 0;
    }
    int pq0 = __shfl(pvA, q3);
    float cvalA = (lane < 48) ? coords[(size_t)pq0 * 3 + e3] : 0.0f;
    float rvalA = (lane < 48) ? ray_d[(size_t)pq0 * 3 + e3] : 0.0f;
    if constexpr (SORTED) pvB = perm[t1 * 64 + wid * 16 + c];
    else                  pvB = t1 * 64 + wid * 16 + c;

    for (int it = 0; it < per; ++it) {
        const int tile = sb * per + it;
        if (tile >= ntiles) break;

        // ---- coords of this lane's point c (from pipelined cvalA) ---------
        float cx = __shfl(cvalA, 3 * c + 0) * 127.0f;
        float cy = __shfl(cvalA, 3 * c + 1) * 127.0f;
        float cz = __shfl(cvalA, 3 * c + 2) * 127.0f;
        int ix = (int)floorf(cx); ix = ix < 0 ? 0 : (ix > 126 ? 126 : ix);
        int iy = (int)floorf(cy); iy = iy < 0 ? 0 : (iy > 126 ? 126 : iy);
        int iz = (int)floorf(cz); iz = iz < 0 ? 0 : (iz > 126 ? 126 : iz);
        float tx = cx - (float)ix;
        float ty = cy - (float)iy;
        float tz = cz - (float)iz;

        // ---- gather: feats[kg*8 .. kg*8+7] of point c (B-frag layout) -----
        f32x4 fa = {0.0f, 0.0f, 0.0f, 0.0f};
        f32x4 fb = {0.0f, 0.0f, 0.0f, 0.0f};
#pragma unroll
        for (int cc = 0; cc < 8; ++cc) {
            int ddx = (cc >> 2) & 1, ddy = (cc >> 1) & 1, ddz = cc & 1;
            float w = (ddx ? tx : 1.0f - tx) *
                      (ddy ? ty : 1.0f - ty) *
                      (ddz ? tz : 1.0f - tz);
            int idx = ((ix + ddx) << 14) + ((iy + ddy) << 7) + (iz + ddz);
            const f32x4* g = (const f32x4*)(grid + (size_t)idx * 32 + kg * 8);
            f32x4 v0 = g[0], v1 = g[1];
#pragma unroll
            for (int e = 0; e < 4; ++e) {
                fa[e] = fmaf(w, v0[e], fa[e]);
                fb[e] = fmaf(w, v1[e], fb[e]);
            }
        }
        BFU b0;
        b0.u[0] = pack2(fa[0], fa[1]); b0.u[1] = pack2(fa[2], fa[3]);
        b0.u[2] = pack2(fb[0], fb[1]); b0.u[3] = pack2(fb[2], fb[3]);

        // ---- prefetch next iteration (overlaps the MLP below) -------------
        float cvalN, rvalN;
        int pvC;
        {
            int pqn = __shfl(pvB, q3);          // pvB loaded last iteration
            cvalN = (lane < 48) ? coords[(size_t)pqn * 3 + e3] : 0.0f;
            rvalN = (lane < 48) ? ray_d[(size_t)pqn * 3 + e3] : 0.0f;
            int t2 = tile + 2; if (t2 >= ntiles) t2 = ntiles - 1;
            if constexpr (SORTED) pvC = perm[t2 * 64 + wid * 16 + c];
            else                  pvC = t2 * 64 + wid * 16 + c;
        }

        // ---- view embedding slots for this lane (dims fixed by kg) --------
        float dxv = __shfl(rvalA, 3 * c + 0);
        float dyv = __shfl(rvalA, 3 * c + 1);
        float dzv = __shfl(rvalA, 3 * c + 2);
        float E0, E1, E2, E3, G0, G1, G2, G3, G4, G5, G6, G7;
        if (kg == 0) {            // E: dims 16-19, G: dims 32-39
            E0 = dxv; E1 = dyv; E2 = dzv; E3 = __sinf(dxv);
            G0 = __cosf(dyv);        G1 = __cosf(dzv);
            G2 = __cosf(2.0f * dxv); G3 = __cosf(2.0f * dyv);
            G4 = __cosf(2.0f * dzv); G5 = __cosf(4.0f * dxv);
            G6 = __cosf(4.0f * dyv); G7 = __cosf(4.0f * dzv);
        } else if (kg == 1) {     // E: dims 20-23, G: dims 40-42 + zeros
            E0 = __sinf(dyv);        E1 = __sinf(dzv);
            E2 = __sinf(2.0f * dxv); E3 = __sinf(2.0f * dyv);
            G0 = __cosf(8.0f * dxv); G1 = __cosf(8.0f * dyv);
            G2 = __cosf(8.0f * dzv);
            G3 = 0.0f; G4 = 0.0f; G5 = 0.0f; G6 = 0.0f; G7 = 0.0f;
        } else if (kg == 2) {     // E: dims 24-27, G: zeros
            E0 = __sinf(2.0f * dzv); E1 = __sinf(4.0f * dxv);
            E2 = __sinf(4.0f * dyv); E3 = __sinf(4.0f * dzv);
            G0 = G1 = G2 = G3 = G4 = G5 = G6 = G7 = 0.0f;
        } else {                  // E: dims 28-31, G: zeros
            E0 = __sinf(8.0f * dxv); E1 = __sinf(8.0f * dyv);
            E2 = __sinf(8.0f * dzv); E3 = __cosf(dxv);
            G0 = G1 = G2 = G3 = G4 = G5 = G6 = G7 = 0.0f;
        }

        // ---- L1: h[16n+4kg+i][c] = wd1^T . feats + bd1 --------------------
        f32x4 acc[8];
#pragma unroll
        for (int n = 0; n < 8; ++n) {
            f32x4 bi = *(const f32x4*)(ldsB1 + n * 16 + kg * 4);
            bf16x8 A = *(const bf16x8*)(lds + n * 1024 + lb);
            acc[n] = __builtin_amdgcn_mfma_f32_16x16x32_bf16(A, b0.v, bi, 0, 0, 0);
        }
        unsigned int pk[8][2];
#pragma unroll
        for (int n = 0; n < 8; ++n) {
            pk[n][0] = pack2(fmaxf(acc[n][0], 0.0f), fmaxf(acc[n][1], 0.0f));
            pk[n][1] = pack2(fmaxf(acc[n][2], 0.0f), fmaxf(acc[n][3], 0.0f));
        }

        // ---- L2: dfeat[4kg+i][c]; split into 2 parallel chains ------------
        f32x4 a2A = *(const f32x4*)(ldsB2 + kg * 4);
        f32x4 a2B = {0.0f, 0.0f, 0.0f, 0.0f};
#pragma unroll
        for (int kt = 0; kt < 4; ++kt) {
            BFU B;
            B.u[0] = pk[2 * kt][0];     B.u[1] = pk[2 * kt][1];
            B.u[2] = pk[2 * kt + 1][0]; B.u[3] = pk[2 * kt + 1][1];
            bf16x8 A = *(const bf16x8*)(lds + (8 + kt) * 1024 + lb);
            if (kt & 1) a2B = __builtin_amdgcn_mfma_f32_16x16x32_bf16(A, B.v, a2B, 0, 0, 0);
            else        a2A = __builtin_amdgcn_mfma_f32_16x16x32_bf16(A, B.v, a2A, 0, 0, 0);
        }
        f32x4 accd = a2A + a2B;
        float dens = fmaxf(accd[0], 0.0f);   // dfeat[0]: valid on kg==0 lanes

        // ---- L3: B(kt3=0) = {dfeat local, E}, B(kt3=1) = {G} --------------
        BFU Bk0, Bk1;
        Bk0.u[0] = pack2(accd[0], accd[1]);
        Bk0.u[1] = pack2(accd[2], accd[3]);
        Bk0.u[2] = pack2(E0, E1);
        Bk0.u[3] = pack2(E2, E3);
        Bk1.u[0] = pack2(G0, G1);
        Bk1.u[1] = pack2(G2, G3);
        Bk1.u[2] = pack2(G4, G5);
        Bk1.u[3] = pack2(G6, G7);

        f32x4 acc3[8];
#pragma unroll
        for (int n = 0; n < 8; ++n) {
            f32x4 bi = *(const f32x4*)(ldsB3 + n * 16 + kg * 4);
            bf16x8 w0 = *(const bf16x8*)(lds + (12 + n * 2 + 0) * 1024 + lb);
            bf16x8 w1 = *(const bf16x8*)(lds + (12 + n * 2 + 1) * 1024 + lb);
            acc3[n] = __builtin_amdgcn_mfma_f32_16x16x32_bf16(w0, Bk0.v, bi, 0, 0, 0);
            acc3[n] = __builtin_amdgcn_mfma_f32_16x16x32_bf16(w1, Bk1.v, acc3[n], 0, 0, 0);
        }
        unsigned int pk3[8][2];
#pragma unroll
        for (int n = 0; n < 8; ++n) {
            pk3[n][0] = pack2(fmaxf(acc3[n][0], 0.0f), fmaxf(acc3[n][1], 0.0f));
            pk3[n][1] = pack2(fmaxf(acc3[n][2], 0.0f), fmaxf(acc3[n][3], 0.0f));
        }

        // ---- L4: rgb[4kg+i][c]; split into 2 parallel chains --------------
        f32x4 a4A = *(const f32x4*)(ldsB4 + kg * 4);
        f32x4 a4B = {0.0f, 0.0f, 0.0f, 0.0f};
#pragma unroll
        for (int kt = 0; kt < 4; ++kt) {
            BFU B;
            B.u[0] = pk3[2 * kt][0];     B.u[1] = pk3[2 * kt][1];
            B.u[2] = pk3[2 * kt + 1][0]; B.u[3] = pk3[2 * kt + 1][1];
            bf16x8 A = *(const bf16x8*)(lds + (28 + kt) * 1024 + lb);
            if (kt & 1) a4B = __builtin_amdgcn_mfma_f32_16x16x32_bf16(A, B.v, a4B, 0, 0, 0);
            else        a4A = __builtin_amdgcn_mfma_f32_16x16x32_bf16(A, B.v, a4A, 0, 0, 0);
        }
        f32x4 acco = a4A + a4B;

        // ---- store: lane (kg==0, c) owns point c completely ---------------
        if (lane < 16) {
            f32x4 o;
            o[0] = 1.0f / (1.0f + __expf(-acco[0]));
            o[1] = 1.0f / (1.0f + __expf(-acco[1]));
            o[2] = 1.0f / (1.0f + __expf(-acco[2]));
            o[3] = dens;
            ((f32x4*)out)[pvA] = o;
        }

        // ---- rotate pipeline ----------------------------------------------
        cvalA = cvalN; rvalA = rvalN;
        pvA = pvB; pvB = pvC;
    }
}

extern "C" void kernel_launch(void* const* d_in, const int* in_sizes, int n_in,
                              void* d_out, int out_size, void* d_ws, size_t ws_size,
                              hipStream_t stream) {
    const float* coords = (const float*)d_in[0];
    const float* ray_d  = (const float*)d_in[1];
    const float* grid   = (const float*)d_in[2];
    const float* wd1    = (const float*)d_in[3];
    const float* bd1    = (const float*)d_in[4];
    const float* wd2    = (const float*)d_in[5];
    const float* bd2    = (const float*)d_in[6];
    const float* wc1    = (const float*)d_in[7];
    const float* bc1    = (const float*)d_in[8];
    const float* wc2    = (const float*)d_in[9];
    const float* bc2    = (const float*)d_in[10];
    float* out = (float*)d_out;

    int N = in_sizes[0] / 3;
    int ntiles = N >> 6;

    char* ws = (char*)d_ws;
    __bf16* wp = (__bf16*)(ws + WS_WP);

    pack_weights<<<1, 256, 0, stream>>>(wd1, wd2, wc1, wc2, wp);

    int blocks = ntiles < 8192 ? ntiles : 8192;

    if (ws_size >= WS_NEED && (N % (HB * 64)) == 0) {
        unsigned int* mat   = (unsigned int*)(ws + WS_MAT);
        unsigned int* total = (unsigned int*)(ws + WS_TOT);
        unsigned int* bbase = (unsigned int*)(ws + WS_BB);
        int* perm = (int*)(ws + WS_PERM);
        int ppb = N / HB;

        hist_lds<<<HB, 256, 0, stream>>>(coords, mat, ppb);
        col_scan<<<NBUCKET / 4, 256, 0, stream>>>(mat, total);
        bucket_scan<<<1, 256, 0, stream>>>(total, bbase);
        scatter_perm<<<HB, 256, 0, stream>>>(coords, mat, bbase, perm, ppb);
        nerf_wave<true><<<blocks, 256, 0, stream>>>(coords, ray_d, grid,
                                                    bd1, bd2, bc1, bc2,
                                                    wp, perm, out, ntiles);
    } else {
        nerf_wave<false><<<blocks, 256, 0, stream>>>(coords, ray_d, grid,
                                                     bd1, bd2, bc1, bc2,
                                                     wp, nullptr, out, ntiles);
    }
}